// Round 3
// baseline (859.262 us; speedup 1.0000x reference)
//
#include <hip/hip_runtime.h>

// L2Similarity: out[n][m] = -||x_n - g_m||, x:[8192,128] f32, g:[16384,128] f32
// NT GEMM via bf16 MFMA (inline f32->bf16 RNE), exact f32 norms, fused epilogue.
// R3 vs R2: wave = 32-row band (acc[2][8]); epilogue transposes through LDS
// (aliased over staging tiles) so stores are global_store_dwordx4, each writing
// two full 512B output rows — 16 store instrs/thread instead of 64 scattered
// scalar dwords. Write floor: 512 MiB @ ~6.3 TB/s = ~85 us.

#define N_IMG 8192
#define N_GTS 16384
#define K_DIM 128
#define BM 128
#define BN 128
#define LDS_K 64      // K staged per half
#define LDAH 72       // 64 + 8 pad shorts (row stride 144B, 16B-aligned)
#define SCR_W 132     // scratch row stride in floats (528B, 16B-aligned, bank-spread)

typedef __attribute__((ext_vector_type(8))) short short8;   // 8 bf16 = 4 VGPRs
typedef __attribute__((ext_vector_type(4))) float f32x4;

__device__ __forceinline__ unsigned short f2bf(float x) {
    unsigned int u = __float_as_uint(x);
    u += 0x7FFFu + ((u >> 16) & 1u);
    return (unsigned short)(u >> 16);
}

union SMem {
    struct { short a[BM][LDAH]; short b[BN][LDAH]; } t;   // 36,864 B staging
    float scratch[4][16][SCR_W];                          // 33,792 B epilogue (aliased)
};

__global__ __launch_bounds__(256, 2)
void l2sim_kernel(const float* __restrict__ A, const float* __restrict__ G,
                  float* __restrict__ out)
{
    __shared__ SMem sm;
    __shared__ float xsq_s[2][BM];   // per-half partial row norms
    __shared__ float gsq_s[2][BN];

    const int t  = threadIdx.x;
    const int bm = blockIdx.y;       // 0..63
    const int bn = blockIdx.x;       // 0..127

    const int wave = t >> 6;
    const int lane = t & 63;
    const int lm   = lane & 15;
    const int quad = lane >> 4;
    const int band = wave * 32;      // wave's 32 output rows within the 128-tile

    f32x4 acc[2][8] = {};            // [mi band-half][ni], rows band+mi*16+quad*4+r, col ni*16+lm

    #pragma unroll
    for (int h = 0; h < 2; ++h) {
        if (h) __syncthreads();      // previous half's MFMA readers done

        // ---- stage A half: 128 rows x 64 K -> bf16 LDS + exact f32 partial sumsq ----
        {
            const float* gA = A + (size_t)bm * BM * K_DIM + h * LDS_K;
            #pragma unroll
            for (int i = 0; i < 8; ++i) {
                int f = i * 256 + t, row = f >> 4, c4 = f & 15;
                float4 v = *(const float4*)(gA + (size_t)row * K_DIM + c4 * 4);
                float s = v.x*v.x + v.y*v.y + v.z*v.z + v.w*v.w;
                s += __shfl_down(s, 8, 16);
                s += __shfl_down(s, 4, 16);
                s += __shfl_down(s, 2, 16);
                s += __shfl_down(s, 1, 16);
                short4 bv;
                bv.x = (short)f2bf(v.x); bv.y = (short)f2bf(v.y);
                bv.z = (short)f2bf(v.z); bv.w = (short)f2bf(v.w);
                *(short4*)&sm.t.a[row][c4 * 4] = bv;
                if ((t & 15) == 0) xsq_s[h][row] = s;
            }
        }
        // ---- stage B half ----
        {
            const float* gB = G + (size_t)bn * BN * K_DIM + h * LDS_K;
            #pragma unroll
            for (int i = 0; i < 8; ++i) {
                int f = i * 256 + t, row = f >> 4, c4 = f & 15;
                float4 v = *(const float4*)(gB + (size_t)row * K_DIM + c4 * 4);
                float s = v.x*v.x + v.y*v.y + v.z*v.z + v.w*v.w;
                s += __shfl_down(s, 8, 16);
                s += __shfl_down(s, 4, 16);
                s += __shfl_down(s, 2, 16);
                s += __shfl_down(s, 1, 16);
                short4 bv;
                bv.x = (short)f2bf(v.x); bv.y = (short)f2bf(v.y);
                bv.z = (short)f2bf(v.z); bv.w = (short)f2bf(v.w);
                *(short4*)&sm.t.b[row][c4 * 4] = bv;
                if ((t & 15) == 0) gsq_s[h][row] = s;
            }
        }
        __syncthreads();

        // ---- MFMA: 2 k-steps of 32; wave does 2x8 16x16 tiles (32 rows x 128 cols) ----
        #pragma unroll
        for (int ks = 0; ks < 2; ++ks) {
            short8 af[2], bfr[8];
            #pragma unroll
            for (int mi = 0; mi < 2; ++mi)
                af[mi] = *(const short8*)&sm.t.a[band + mi * 16 + lm][ks * 32 + quad * 8];
            #pragma unroll
            for (int ni = 0; ni < 8; ++ni)
                bfr[ni] = *(const short8*)&sm.t.b[ni * 16 + lm][ks * 32 + quad * 8];
            #pragma unroll
            for (int mi = 0; mi < 2; ++mi)
                #pragma unroll
                for (int ni = 0; ni < 8; ++ni)
                    acc[mi][ni] = __builtin_amdgcn_mfma_f32_16x16x32_bf16(
                        af[mi], bfr[ni], acc[mi][ni], 0, 0, 0);
        }
    }

    // ---- pull norms into registers (norm arrays are NOT aliased) ----
    float gs[8], xs[2][4];
    #pragma unroll
    for (int ni = 0; ni < 8; ++ni) {
        int n = ni * 16 + lm;
        gs[ni] = gsq_s[0][n] + gsq_s[1][n];
    }
    #pragma unroll
    for (int mi = 0; mi < 2; ++mi)
        #pragma unroll
        for (int r = 0; r < 4; ++r) {
            int m = band + mi * 16 + quad * 4 + r;
            xs[mi][r] = xsq_s[0][m] + xsq_s[1][m];
        }

    __syncthreads();   // all waves done reading staging tiles -> scratch may alias

    // ---- epilogue: -sqrt in regs, per-wave LDS transpose, dwordx4 row stores ----
    float* outBase = out + (size_t)(bm * BM) * N_GTS + (size_t)(bn * BN);
    #pragma unroll
    for (int mi = 0; mi < 2; ++mi) {
        // write 16 rows x 128 cols of finished values (2-way bank alias: free)
        #pragma unroll
        for (int ni = 0; ni < 8; ++ni)
            #pragma unroll
            for (int r = 0; r < 4; ++r) {
                float d2 = fmaxf(xs[mi][r] + gs[ni] - 2.0f * acc[mi][ni][r], 0.0f);
                sm.scratch[wave][quad * 4 + r][ni * 16 + lm] = -sqrtf(d2);
            }
        // read back row-contiguous: lane covers 4 consecutive cols; one store = 2 full rows
        #pragma unroll
        for (int i = 0; i < 8; ++i) {
            int r = i * 2 + (lane >> 5);          // 0..15 within the 16-row pass
            int c = (lane & 31) * 4;              // 0..124
            f32x4 v = *(const f32x4*)&sm.scratch[wave][r][c];
            int gr = band + mi * 16 + r;          // global row within 128-tile
            *(f32x4*)(outBase + (size_t)gr * N_GTS + c) = v;
        }
    }
}

extern "C" void kernel_launch(void* const* d_in, const int* in_sizes, int n_in,
                              void* d_out, int out_size, void* d_ws, size_t ws_size,
                              hipStream_t stream) {
    const float* A = (const float*)d_in[0];   // image_features [8192,128]
    const float* G = (const float*)d_in[1];   // gts            [16384,128]
    float* out = (float*)d_out;               // [8192,16384]
    dim3 grid(N_GTS / BN, N_IMG / BM);        // (128, 64)
    l2sim_kernel<<<grid, 256, 0, stream>>>(A, G, out);
}